// Round 6
// baseline (205.717 us; speedup 1.0000x reference)
//
#include <hip/hip_runtime.h>
#include <stdint.h>

#define Bn 4
#define Cn 256
#define Gn 32
#define Nn 4096
#define CGn 8

typedef unsigned short u16;
typedef __attribute__((ext_vector_type(8))) short short8;
typedef __attribute__((ext_vector_type(4))) short short4v;
typedef __attribute__((ext_vector_type(4))) float f32x4;
typedef __attribute__((ext_vector_type(16))) float f32x16;

__device__ __forceinline__ u16 f2bf(float x) {
  uint32_t u = __float_as_uint(x);
  u += 0x7fffu + ((u >> 16) & 1u);
  return (u16)(u >> 16);
}
__device__ __forceinline__ float b2f(u16 v) {
  return __uint_as_float(((uint32_t)v) << 16);
}

// async global->LDS, 16B per lane; lds base must be wave-uniform
__device__ __forceinline__ void gl_lds16(const void* g, void* l) {
  __builtin_amdgcn_global_load_lds(
      (__attribute__((address_space(1))) void*)(uintptr_t)g,
      (__attribute__((address_space(3))) void*)(uintptr_t)l, 16, 0, 0);
}

// XOR-swizzled tile addressing (proj GEMM): rows of 512B (32 x 16B chunks)
__device__ __forceinline__ int sw512(int row, int cb) { return row * 512 + ((cb ^ (row & 7)) * 16); }

// ---------------- fused weight-convert + GN stats ----------------------------
__global__ void k_cs(const float* __restrict__ wq, const float* __restrict__ wk,
                     const float* __restrict__ wv, const float* __restrict__ wp,
                     const float* __restrict__ bq, const float* __restrict__ bk,
                     const float* __restrict__ bv, const float* __restrict__ x,
                     u16* __restrict__ wqkv, u16* __restrict__ wpb,
                     float* __restrict__ bqkv, float* __restrict__ stats) {
  if (blockIdx.x < 256) {
    const float s = 0.09016844005556021f;  // log2(e) / sqrt(256)
    int i = blockIdx.x * 256 + threadIdx.x;
    wqkv[i]          = f2bf(wq[i] * s);
    wqkv[i + 65536]  = f2bf(wk[i]);
    wqkv[i + 131072] = f2bf(wv[i]);
    wpb[i]           = f2bf(wp[i]);
    if (i < 256) { bqkv[i] = bq[i] * s; bqkv[i + 256] = bk[i]; bqkv[i + 512] = bv[i]; }
  } else {
    int blk = blockIdx.x - 256;     // (b*32+g)*4 + part
    int grp = blk >> 2, part = blk & 3;
    const float4* base = (const float4*)(x + (size_t)grp * (CGn * Nn) + part * 8192);
    float s = 0.f, s2 = 0.f;
    for (int i = threadIdx.x; i < 2048; i += 256) {
      float4 v = base[i];
      s  += v.x + v.y + v.z + v.w;
      s2 += v.x * v.x + v.y * v.y + v.z * v.z + v.w * v.w;
    }
#pragma unroll
    for (int m = 1; m < 64; m <<= 1) { s += __shfl_xor(s, m, 64); s2 += __shfl_xor(s2, m, 64); }
    __shared__ float ps[4], ps2[4];
    int w = threadIdx.x >> 6;
    if ((threadIdx.x & 63) == 0) { ps[w] = s; ps2[w] = s2; }
    __syncthreads();
    if (threadIdx.x == 0) {
      stats[grp * 8 + part * 2]     = ps[0] + ps[1] + ps[2] + ps[3];
      stats[grp * 8 + part * 2 + 1] = ps2[0] + ps2[1] + ps2[2] + ps2[3];
    }
  }
}

// ---------------- GN apply -> hnT (N,C) bf16, coalesced via LDS transpose ----
__global__ void k_apply(const float* __restrict__ x, const float* __restrict__ stats,
                        const float* __restrict__ gsc, const float* __restrict__ gbi,
                        u16* __restrict__ hnT) {
  __shared__ __align__(16) char smem[32768];  // 64 n-rows x 512B (c), rotated
  __shared__ float smu[Gn], srs[Gn];
  int n0 = blockIdx.x * 64;
  int b = blockIdx.y;
  int tid = threadIdx.x;
  if (tid < Gn) {
    float S = 0.f, S2 = 0.f;
#pragma unroll
    for (int p = 0; p < 4; ++p) {
      S  += stats[(b * Gn + tid) * 8 + p * 2];
      S2 += stats[(b * Gn + tid) * 8 + p * 2 + 1];
    }
    const float inv = 1.f / (CGn * Nn);
    float mu = S * inv;
    float var = S2 * inv - mu * mu;
    smu[tid] = mu;
    srs[tid] = rsqrtf(var + 1e-6f);
  }
  __syncthreads();
  int nl = (tid & 15) * 4;
  int cbase = tid >> 4;
  for (int pass = 0; pass < 16; ++pass) {
    int c = pass * 16 + cbase;
    float4 v = *(const float4*)(x + (size_t)b * Cn * Nn + (size_t)c * Nn + n0 + nl);
    int g = c >> 3;
    float sc = gsc[c] * srs[g];
    float bi = gbi[c] - smu[g] * sc;
    float vals[4] = {v.x, v.y, v.z, v.w};
#pragma unroll
    for (int i = 0; i < 4; ++i) {
      int row = nl + i;
      int off = row * 512 + ((((c >> 3) + row) & 31) * 16) + (c & 7) * 2;
      *(u16*)(smem + off) = f2bf(vals[i] * sc + bi);
    }
  }
  __syncthreads();
#pragma unroll
  for (int p = 0; p < 8; ++p) {
    int idx = p * 256 + tid;   // 2048 chunk-slots
    int row = idx >> 5, pc = idx & 31;
    int gc = (pc - row) & 31;
    short8 v8 = *(const short8*)(smem + row * 512 + pc * 16);
    *(short8*)(hnT + ((size_t)b * Nn + n0 + row) * Cn + gc * 8) = v8;
  }
}

// ---------------- QKV GEMM v3: stage hn tile ONCE, loop all 12 d-groups ------
// 32-n-row blocks (512 total, 2/CU). hnT read exactly once (was 12x). W frags
// loaded from global per d-group (wqkv 384KB, L2-resident — pattern proven in
// k_proj R3/R4). Barrier-free after the initial stage; per-wave scratch.
__global__ __launch_bounds__(256, 4)
void k_qkv(const u16* __restrict__ wqkv, const float* __restrict__ bqkv,
           const u16* __restrict__ hnT, u16* __restrict__ qT, u16* __restrict__ kT,
           u16* __restrict__ vv) {
  __shared__ __align__(16) char smem[24576];  // 16KB hn tile + 4 x 2KB scratch
  const int tid = threadIdx.x, lane = tid & 63, w = tid >> 6;
  const int quad = (lane >> 4) & 3, low = lane & 15;
  const int n0 = blockIdx.x * 32, b = blockIdx.y;
  const u16* hb = hnT + (size_t)b * Nn * Cn;
  // stage 32 n-rows x 512B, rotated chunk image (chunk c of row r holds
  // global chunk (c - r) & 31)
  {
    int lo = lane & 31;
#pragma unroll
    for (int s = 0; s < 4; ++s) {
      int r = w * 8 + s * 2 + (lane >> 5);
      int gc = (lo - r) & 31;
      gl_lds16(hb + (size_t)(n0 + r) * Cn + gc * 8, smem + (w * 8 + s * 2) * 512);
    }
  }
  asm volatile("s_waitcnt vmcnt(0)" ::: "memory");
  __syncthreads();
  char* Q = smem + 16384 + w * 2048;   // wave-private scratch
  for (int dg = 0; dg < 12; ++dg) {
    // W A-frags: af[kk][e] = W[dg*64 + w*16 + low][kk*32 + quad*8 + e]
    short8 af[8];
    {
      const u16* wrow = wqkv + (size_t)(dg * 64 + w * 16 + low) * Cn + quad * 8;
#pragma unroll
      for (int kk = 0; kk < 8; ++kk) af[kk] = *(const short8*)(wrow + kk * 32);
    }
    float bias[4];
#pragma unroll
    for (int r = 0; r < 4; ++r) bias[r] = bqkv[dg * 64 + w * 16 + quad * 4 + r];
    f32x4 acc[2] = {{0.f,0.f,0.f,0.f},{0.f,0.f,0.f,0.f}};
#pragma unroll
    for (int kk = 0; kk < 8; ++kk)
#pragma unroll
      for (int t = 0; t < 2; ++t) {
        int row = t * 16 + low;
        short8 bf = *(const short8*)(smem + row * 512 + (((kk * 4 + quad) + row) & 31) * 16);
        acc[t] = __builtin_amdgcn_mfma_f32_16x16x32_bf16(af[kk], bf, acc[t], 0, 0, 0);
      }
    int which = dg >> 2, dl0 = (dg & 3) * 64;
    if (which == 2) {
      // v: 16 d-rows x 72B scratch (32 n ascending), then (c,n) 16B stores
#pragma unroll
      for (int t = 0; t < 2; ++t)
#pragma unroll
        for (int rp = 0; rp < 2; ++rp) {
          uint32_t wv2;
          float f0 = acc[t][2 * rp] + bias[2 * rp];
          float f1 = acc[t][2 * rp + 1] + bias[2 * rp + 1];
          asm("v_cvt_pk_bf16_f32 %0, %1, %2" : "=v"(wv2) : "v"(f0), "v"(f1));
          *(u16*)(Q + (quad * 4 + 2 * rp) * 72 + t * 32 + low * 2) = (u16)wv2;
          *(u16*)(Q + (quad * 4 + 2 * rp + 1) * 72 + t * 32 + low * 2) = (u16)(wv2 >> 16);
        }
      {
        int row = lane >> 2, ch = lane & 3;   // 16 d-rows x 4 chunks
        short8 v8 = *(const short8*)(Q + row * 72 + ch * 16);
        *(short8*)(vv + (size_t)b * Cn * Nn + (size_t)(dl0 + w * 16 + row) * Nn +
                   n0 + ch * 8) = v8;
      }
    } else {
      // q/k: 32 n-rows x 48B scratch (16 d bf16 in bytes 0..32)
#pragma unroll
      for (int t = 0; t < 2; ++t) {
        union { uint32_t u[2]; short4v s; } pk;
        float f0 = acc[t][0] + bias[0], f1 = acc[t][1] + bias[1];
        float f2 = acc[t][2] + bias[2], f3 = acc[t][3] + bias[3];
        asm("v_cvt_pk_bf16_f32 %0, %1, %2" : "=v"(pk.u[0]) : "v"(f0), "v"(f1));
        asm("v_cvt_pk_bf16_f32 %0, %1, %2" : "=v"(pk.u[1]) : "v"(f2), "v"(f3));
        *(short4v*)(Q + (t * 16 + low) * 48 + quad * 8) = pk.s;
      }
      u16* dst = (which == 0 ? qT : kT) + (size_t)b * Nn * Cn;
      {
        int row = lane >> 1, half = lane & 1;  // 32 n-rows x 2 halves
        short8 v8 = *(const short8*)(Q + row * 48 + half * 16);
        *(short8*)(dst + (size_t)(n0 + row) * Cn + dl0 + w * 16 + half * 8) = v8;
      }
    }
  }
}

// ---------------- flash attention, pipelined double-buffered K-loop (R1) -----
// NOTE: this kernel is at its VGPR ceiling (Oa[8]=128 f32 + qf[16]=64).
// Adding live state spills (~+22us, R2). Halving block/LDS raises L2 staging
// pressure faster than overlap (+8us, R5). Proven local optimum — keep as-is.
__device__ __forceinline__ void flash_stage(char* smem, int bsel, const u16* kTb,
                                            const u16* vb, int j0, int w, int lo,
                                            int kr, int vr, int vp) {
  char* ksb = smem + bsel * 32768;
  char* vsb = ksb + 16384;
#pragma unroll
  for (int s = 0; s < 4; ++s) {   // ks: 32 rows x 512B, row-rotated chunks
    int j = kr + s * 2;
    int gc = (lo - j) & 31;
    gl_lds16(kTb + (size_t)(j0 + j) * Cn + gc * 8, ksb + (w * 8 + s * 2) * 512);
  }
#pragma unroll
  for (int s = 0; s < 4; ++s) {   // vs: 256 rows x 64B, rot(c)=c+(c>>2)
    int c = vr + s * 16;
    int gc = (vp - c - (c >> 2)) & 3;
    gl_lds16(vb + (size_t)c * Nn + j0 + gc * 8, vsb + (w * 64 + s * 16) * 64);
  }
}

__global__ __launch_bounds__(256, 2)
void k_flash(const u16* __restrict__ qT, const u16* __restrict__ kT,
             const u16* __restrict__ vv, u16* __restrict__ Op0,
             u16* __restrict__ Op1, u16* __restrict__ Op2, u16* __restrict__ Op3,
             float* __restrict__ lrow) {
  __shared__ __align__(16) char smem[65536];
  const int tid = threadIdx.x, lane = tid & 63, w = tid >> 6;
  const int lo = lane & 31, hi = lane >> 5;
  const int i0 = blockIdx.x * 128;
  const int b = blockIdx.y, jh = blockIdx.z;
  const u16* qTb = qT + (size_t)b * Nn * Cn;
  const u16* kTb = kT + (size_t)b * Nn * Cn;
  const u16* vb  = vv + (size_t)b * Cn * Nn;
  const int u7 = lo + hi;
  const int u9 = lo + hi + (lo >> 2);   // vs read rotation
  const int kr = w * 8 + hi;
  const int vr = w * 64 + (lane >> 2);
  const int vp = lane & 3;

  flash_stage(smem, 0, kTb, vb, jh * 1024, w, lo, kr, vr, vp);

  // q B-frags: lane holds q[i = i0+w*32+lo][c = ks*16 + hi*8 + e]
  short8 qf[16];
  {
    const u16* qrow = qTb + (size_t)(i0 + w * 32 + lo) * Cn + hi * 8;
#pragma unroll
    for (int ks = 0; ks < 16; ++ks) qf[ks] = *(const short8*)(qrow + ks * 16);
  }
  f32x16 Oa[8];
#pragma unroll
  for (int ct = 0; ct < 8; ++ct)
#pragma unroll
    for (int e = 0; e < 16; ++e) Oa[ct][e] = 0.f;
  float l_ = 0.f;

  for (int jt = 0; jt < 32; ++jt) {
    if (jt < 31) {
      flash_stage(smem, (jt + 1) & 1, kTb, vb, jh * 1024 + (jt + 1) * 32, w, lo, kr, vr, vp);
      asm volatile("s_waitcnt vmcnt(8)" ::: "memory");   // only the older 8 (current tile)
    } else {
      asm volatile("s_waitcnt vmcnt(0)" ::: "memory");
    }
    asm volatile("s_barrier" ::: "memory");              // raw: no vmcnt(0) drain
    const char* ksb = smem + (jt & 1) * 32768;
    const char* vsb = ksb + 16384;

    // S^T = K·q : D[m=j 32][n=i 32], A = ks (rotated), B = qf
    f32x16 S0;
#pragma unroll
    for (int e = 0; e < 16; ++e) S0[e] = 0.f;
    __builtin_amdgcn_s_setprio(1);
#pragma unroll
    for (int ks = 0; ks < 16; ++ks) {
      int ch = (ks * 2 + u7) & 31;
      short8 a0 = *(const short8*)(ksb + lo * 512 + ch * 16);
      S0 = __builtin_amdgcn_mfma_f32_32x32x16_bf16(a0, qf[ks], S0, 0, 0, 0);
    }
    __builtin_amdgcn_s_setprio(0);
    // P = exp2(S), pack bf16 pairs via v_cvt_pk_bf16_f32, per-lane l
    uint32_t Pp[8];
#pragma unroll
    for (int g = 0; g < 8; ++g) {
      float p0 = __builtin_amdgcn_exp2f(S0[2 * g]);
      float p1 = __builtin_amdgcn_exp2f(S0[2 * g + 1]);
      l_ += p0 + p1;
      asm("v_cvt_pk_bf16_f32 %0, %1, %2" : "=v"(Pp[g]) : "v"(p0), "v"(p1));
    }
    // PV: O^T[m=c][n=i] += V·P ; P B-frag via permlane32_swap half exchange
#pragma unroll
    for (int kst = 0; kst < 2; ++kst) {
      uint32_t x0 = Pp[4 * kst], x1 = Pp[4 * kst + 1];
      uint32_t y0 = Pp[4 * kst + 2], y1 = Pp[4 * kst + 3];
      asm("v_permlane32_swap_b32 %0, %1" : "+v"(x0), "+v"(y0));
      asm("v_permlane32_swap_b32 %0, %1" : "+v"(x1), "+v"(y1));
      union { uint32_t u[4]; short8 s8; } pu;
      pu.u[0] = x0;
      pu.u[1] = x1;
      pu.u[2] = y0;
      pu.u[3] = y1;
      int ch = (kst * 2 + u9) & 3;
      __builtin_amdgcn_s_setprio(1);
#pragma unroll
      for (int ct = 0; ct < 8; ++ct) {
        short8 vf = *(const short8*)(vsb + (ct * 32 + lo) * 64 + ch * 16);
        Oa[ct] = __builtin_amdgcn_mfma_f32_32x32x16_bf16(vf, pu.s8, Oa[ct], 0, 0, 0);
      }
      __builtin_amdgcn_s_setprio(0);
    }
    asm volatile("s_barrier" ::: "memory");              // readers done before restage
  }

  // l: lane pair holds complementary j halves
  l_ += __shfl_xor(l_, 32, 64);
  if (hi == 0)
    lrow[(size_t)jh * (Bn * Nn) + (size_t)b * Nn + i0 + w * 32 + lo] = l_;
  float invl = __builtin_amdgcn_rcpf(l_);
  __syncthreads();  // loop drained (vmcnt(0) at last iter); reuse all 64KB
#pragma unroll
  for (int ct = 0; ct < 8; ++ct)
#pragma unroll
    for (int g = 0; g < 4; ++g) {
      union { uint32_t u[2]; short4v s; } pk;
      float f0 = Oa[ct][g * 4 + 0] * invl, f1 = Oa[ct][g * 4 + 1] * invl;
      float f2 = Oa[ct][g * 4 + 2] * invl, f3 = Oa[ct][g * 4 + 3] * invl;
      asm("v_cvt_pk_bf16_f32 %0, %1, %2" : "=v"(pk.u[0]) : "v"(f0), "v"(f1));
      asm("v_cvt_pk_bf16_f32 %0, %1, %2" : "=v"(pk.u[1]) : "v"(f2), "v"(f3));
      int chv = (ct * 4 + g + lo) & 31;
      *(short4v*)(smem + w * 16384 + lo * 512 + chv * 16 + hi * 8) = pk.s;
    }
  __syncthreads();
  u16* Opj = (jh == 0) ? Op0 : (jh == 1) ? Op1 : (jh == 2) ? Op2 : Op3;
  u16* Ob = Opj + ((size_t)b * Nn + i0 + w * 32) * (size_t)Cn;
#pragma unroll
  for (int s = 0; s < 16; ++s) {
    int rr = s * 2 + hi;
    short8 v8 = *(const short8*)(smem + w * 16384 + rr * 512 + lo * 16);
    int gc = (lo - rr) & 31;
    *(short8*)(Ob + (size_t)rr * Cn + gc * 8) = v8;
  }
}

// ---------------- proj GEMM + bias + residual, fused combine, d-loop ---------
__global__ __launch_bounds__(256, 2)
void k_proj(const u16* __restrict__ wpb, const float* __restrict__ bp,
            const u16* __restrict__ O0, const u16* __restrict__ O1,
            const u16* __restrict__ O2, const u16* __restrict__ O3,
            const float* __restrict__ lrow,
            const float* __restrict__ x, float* __restrict__ out) {
  __shared__ __align__(16) char smem[16384];  // 32 n-rows x 512B, swizzled
  int tid = threadIdx.x, lane = tid & 63, w = tid >> 6, quad = lane >> 4, low = lane & 15;
  int n0 = blockIdx.x * 32, b = blockIdx.z;
  // combine the 4 attention partials into B tile (once per n-strip)
#pragma unroll
  for (int p = 0; p < 4; ++p) {
    int slot = p * 256 + tid;          // 1024 chunk-slots (32 rows x 32 chunks)
    int row = slot >> 5, pc = slot & 31;
    int gcb = pc ^ (row & 7);
    size_t gbase = ((size_t)b * Nn + n0 + row) * Cn + gcb * 8;
    short8 a0 = *(const short8*)(O0 + gbase);
    short8 a1 = *(const short8*)(O1 + gbase);
    short8 a2 = *(const short8*)(O2 + gbase);
    short8 a3 = *(const short8*)(O3 + gbase);
    int rrow = b * Nn + n0 + row;
    float L = lrow[rrow] + lrow[Bn * Nn + rrow] + lrow[2 * Bn * Nn + rrow] +
              lrow[3 * Bn * Nn + rrow];
    float inv = __builtin_amdgcn_rcpf(L);
    short8 o;
#pragma unroll
    for (int i = 0; i < 8; ++i)
      o[i] = (short)f2bf((b2f((u16)a0[i]) + b2f((u16)a1[i]) + b2f((u16)a2[i]) +
                          b2f((u16)a3[i])) * inv);
    *(short8*)(smem + row * 512 + pc * 16) = o;
  }
  __syncthreads();
  // d-group loop: W in registers (global loads, L2-hot); barrier-free
  for (int dg = 0; dg < 4; ++dg) {
    short8 af[8];
    {
      const u16* wrow = wpb + (size_t)(dg * 64 + w * 16 + low) * Cn + quad * 8;
#pragma unroll
      for (int kk = 0; kk < 8; ++kk) af[kk] = *(const short8*)(wrow + kk * 32);
    }
    f32x4 acc[2] = {{0.f,0.f,0.f,0.f},{0.f,0.f,0.f,0.f}};
#pragma unroll
    for (int kk = 0; kk < 8; ++kk)
#pragma unroll
      for (int t = 0; t < 2; ++t) {
        short8 bf = *(const short8*)(smem + sw512(t * 16 + low, kk * 4 + quad));
        acc[t] = __builtin_amdgcn_mfma_f32_16x16x32_bf16(af[kk], bf, acc[t], 0, 0, 0);
      }
    int dloc = dg * 64 + w * 16 + quad * 4;
#pragma unroll
    for (int t = 0; t < 2; ++t)
#pragma unroll
      for (int r = 0; r < 4; ++r) {
        size_t idx = (size_t)b * Cn * Nn + (size_t)(dloc + r) * Nn + n0 + t * 16 + low;
        out[idx] = x[idx] + acc[t][r] + bp[dloc + r];
      }
  }
}

// ---------------- launcher ----------------------------------------------------
extern "C" void kernel_launch(void* const* d_in, const int* in_sizes, int n_in,
                              void* d_out, int out_size, void* d_ws, size_t ws_size,
                              hipStream_t stream) {
  const float* x   = (const float*)d_in[0];
  const float* gsc = (const float*)d_in[1];
  const float* gbi = (const float*)d_in[2];
  const float* wq  = (const float*)d_in[3];
  const float* bq  = (const float*)d_in[4];
  const float* wk  = (const float*)d_in[5];
  const float* bk  = (const float*)d_in[6];
  const float* wv  = (const float*)d_in[7];
  const float* bv  = (const float*)d_in[8];
  const float* wp  = (const float*)d_in[9];
  const float* bp  = (const float*)d_in[10];
  float* out = (float*)d_out;

  char* ws = (char*)d_ws;
  u16*   wqkv  = (u16*)(ws + 0);          // 384 KB
  u16*   wpb   = (u16*)(ws + 393216);     // 128 KB
  float* bqkv  = (float*)(ws + 524288);   // 3 KB
  float* stats = (float*)(ws + 527360);   // 4 KB (per-part slots)
  float* lrow  = (float*)(ws + 532480);   // 256 KB
  u16*   hnT   = (u16*)(ws + 1048576);    // 8 MB; reused as Op0 after qkv
  u16*   qT    = (u16*)(ws + 9437184);    // 8 MB
  u16*   kT    = (u16*)(ws + 17825792);   // 8 MB
  u16*   vv    = (u16*)(ws + 26214400);   // 8 MB
  u16*   Op1   = (u16*)(ws + 34603008);   // 8 MB
  u16*   Op2   = (u16*)(ws + 42991616);   // 8 MB
  u16*   Op3   = (u16*)(ws + 51380224);   // 8 MB; end ~57 MB

  k_cs<<<768, 256, 0, stream>>>(wq, wk, wv, wp, bq, bk, bv, x, wqkv, wpb, bqkv, stats);
  k_apply<<<dim3(64, 4), 256, 0, stream>>>(x, stats, gsc, gbi, hnT);
  k_qkv<<<dim3(128, 4), 256, 0, stream>>>(wqkv, bqkv, hnT, qT, kT, vv);
  k_flash<<<dim3(32, 4, 4), 256, 0, stream>>>(qT, kT, vv, hnT /*Op0*/, Op1, Op2, Op3, lrow);
  k_proj<<<dim3(128, 1, 4), 256, 0, stream>>>(wpb, bp, hnT /*Op0*/, Op1, Op2, Op3, lrow, x, out);
}

// Round 7
// 190.778 us; speedup vs baseline: 1.0783x; 1.0783x over previous
//
#include <hip/hip_runtime.h>
#include <stdint.h>

#define Bn 4
#define Cn 256
#define Gn 32
#define Nn 4096
#define CGn 8

typedef unsigned short u16;
typedef __attribute__((ext_vector_type(8))) short short8;
typedef __attribute__((ext_vector_type(4))) short short4v;
typedef __attribute__((ext_vector_type(4))) float f32x4;
typedef __attribute__((ext_vector_type(16))) float f32x16;

__device__ __forceinline__ u16 f2bf(float x) {
  uint32_t u = __float_as_uint(x);
  u += 0x7fffu + ((u >> 16) & 1u);
  return (u16)(u >> 16);
}
__device__ __forceinline__ float b2f(u16 v) {
  return __uint_as_float(((uint32_t)v) << 16);
}

// async global->LDS, 16B per lane; lds base must be wave-uniform
__device__ __forceinline__ void gl_lds16(const void* g, void* l) {
  __builtin_amdgcn_global_load_lds(
      (__attribute__((address_space(1))) void*)(uintptr_t)g,
      (__attribute__((address_space(3))) void*)(uintptr_t)l, 16, 0, 0);
}

// XOR-swizzled tile addressing (proj GEMM): rows of 512B (32 x 16B chunks)
__device__ __forceinline__ int sw512(int row, int cb) { return row * 512 + ((cb ^ (row & 7)) * 16); }

// ---------------- fused weight-convert + GN stats ----------------------------
__global__ void k_cs(const float* __restrict__ wq, const float* __restrict__ wk,
                     const float* __restrict__ wv, const float* __restrict__ wp,
                     const float* __restrict__ bq, const float* __restrict__ bk,
                     const float* __restrict__ bv, const float* __restrict__ x,
                     u16* __restrict__ wqkv, u16* __restrict__ wpb,
                     float* __restrict__ bqkv, float* __restrict__ stats) {
  if (blockIdx.x < 256) {
    const float s = 0.09016844005556021f;  // log2(e) / sqrt(256)
    int i = blockIdx.x * 256 + threadIdx.x;
    wqkv[i]          = f2bf(wq[i] * s);
    wqkv[i + 65536]  = f2bf(wk[i]);
    wqkv[i + 131072] = f2bf(wv[i]);
    wpb[i]           = f2bf(wp[i]);
    if (i < 256) { bqkv[i] = bq[i] * s; bqkv[i + 256] = bk[i]; bqkv[i + 512] = bv[i]; }
  } else {
    int blk = blockIdx.x - 256;     // (b*32+g)*4 + part
    int grp = blk >> 2, part = blk & 3;
    const float4* base = (const float4*)(x + (size_t)grp * (CGn * Nn) + part * 8192);
    float s = 0.f, s2 = 0.f;
    for (int i = threadIdx.x; i < 2048; i += 256) {
      float4 v = base[i];
      s  += v.x + v.y + v.z + v.w;
      s2 += v.x * v.x + v.y * v.y + v.z * v.z + v.w * v.w;
    }
#pragma unroll
    for (int m = 1; m < 64; m <<= 1) { s += __shfl_xor(s, m, 64); s2 += __shfl_xor(s2, m, 64); }
    __shared__ float ps[4], ps2[4];
    int w = threadIdx.x >> 6;
    if ((threadIdx.x & 63) == 0) { ps[w] = s; ps2[w] = s2; }
    __syncthreads();
    if (threadIdx.x == 0) {
      stats[grp * 8 + part * 2]     = ps[0] + ps[1] + ps[2] + ps[3];
      stats[grp * 8 + part * 2 + 1] = ps2[0] + ps2[1] + ps2[2] + ps2[3];
    }
  }
}

// ---------------- GN apply -> hnT (N,C) bf16, coalesced via LDS transpose ----
__global__ void k_apply(const float* __restrict__ x, const float* __restrict__ stats,
                        const float* __restrict__ gsc, const float* __restrict__ gbi,
                        u16* __restrict__ hnT) {
  __shared__ __align__(16) char smem[32768];  // 64 n-rows x 512B (c), rotated
  __shared__ float smu[Gn], srs[Gn];
  int n0 = blockIdx.x * 64;
  int b = blockIdx.y;
  int tid = threadIdx.x;
  if (tid < Gn) {
    float S = 0.f, S2 = 0.f;
#pragma unroll
    for (int p = 0; p < 4; ++p) {
      S  += stats[(b * Gn + tid) * 8 + p * 2];
      S2 += stats[(b * Gn + tid) * 8 + p * 2 + 1];
    }
    const float inv = 1.f / (CGn * Nn);
    float mu = S * inv;
    float var = S2 * inv - mu * mu;
    smu[tid] = mu;
    srs[tid] = rsqrtf(var + 1e-6f);
  }
  __syncthreads();
  int nl = (tid & 15) * 4;
  int cbase = tid >> 4;
  for (int pass = 0; pass < 16; ++pass) {
    int c = pass * 16 + cbase;
    float4 v = *(const float4*)(x + (size_t)b * Cn * Nn + (size_t)c * Nn + n0 + nl);
    int g = c >> 3;
    float sc = gsc[c] * srs[g];
    float bi = gbi[c] - smu[g] * sc;
    float vals[4] = {v.x, v.y, v.z, v.w};
#pragma unroll
    for (int i = 0; i < 4; ++i) {
      int row = nl + i;
      int off = row * 512 + ((((c >> 3) + row) & 31) * 16) + (c & 7) * 2;
      *(u16*)(smem + off) = f2bf(vals[i] * sc + bi);
    }
  }
  __syncthreads();
#pragma unroll
  for (int p = 0; p < 8; ++p) {
    int idx = p * 256 + tid;   // 2048 chunk-slots
    int row = idx >> 5, pc = idx & 31;
    int gc = (pc - row) & 31;
    short8 v8 = *(const short8*)(smem + row * 512 + pc * 16);
    *(short8*)(hnT + ((size_t)b * Nn + n0 + row) * Cn + gc * 8) = v8;
  }
}

// ---------------- QKV GEMM v2: W in registers, streamed hn, pipelined --------
// (Proven best: v3 stage-once/d-loop variant cost +13us — latency-bound on
// serial W-frag loads. Keep v2's 4-tile pipelined structure.)
__global__ __launch_bounds__(256, 2)
void k_qkv(const u16* __restrict__ wqkv, const float* __restrict__ bqkv,
           const u16* __restrict__ hnT, u16* __restrict__ qT, u16* __restrict__ kT,
           u16* __restrict__ vv) {
  __shared__ __align__(16) char smem[65536];
  const int tid = threadIdx.x, lane = tid & 63, w = tid >> 6;
  const int quad = (lane >> 4) & 3, low = lane & 15;
  const int d0 = blockIdx.y * 64, b = blockIdx.z;
  const int n_base = blockIdx.x * 256;
  const int which = d0 >> 8;
  const int dl0 = d0 & 255;
  const u16* hb = hnT + (size_t)b * Nn * Cn;
  const int scol = lane & 31;

#define QKV_STAGE(bsel, nt)                                                     \
  {                                                                             \
    _Pragma("unroll") for (int s = 0; s < 8; ++s) {                             \
      int r = w * 16 + s * 2 + (lane >> 5);                                     \
      int gc = (scol - r) & 31;                                                 \
      gl_lds16(hb + (size_t)(n_base + (nt) * 64 + r) * Cn + gc * 8,             \
               smem + (bsel) * 32768 + (w * 16 + s * 2) * 512);                 \
    }                                                                           \
  }

  QKV_STAGE(0, 0);
  // W A-frags in registers: af[kk][e] = W[d0+w*16+low][kk*32 + quad*8 + e]
  short8 af[8];
  {
    const u16* wrow = wqkv + (size_t)(d0 + w * 16 + low) * Cn + quad * 8;
#pragma unroll
    for (int kk = 0; kk < 8; ++kk) af[kk] = *(const short8*)(wrow + kk * 32);
  }
  float bias[4];
#pragma unroll
  for (int r = 0; r < 4; ++r) bias[r] = bqkv[d0 + w * 16 + quad * 4 + r];

  for (int nt = 0; nt < 4; ++nt) {
    if (nt < 3) {
      QKV_STAGE((nt + 1) & 1, nt + 1);
      asm volatile("s_waitcnt vmcnt(10)" ::: "memory");  // drain stage(nt), skip 2 ep stores + stage(nt+1)
    } else {
      asm volatile("s_waitcnt vmcnt(0)" ::: "memory");
    }
    asm volatile("s_barrier" ::: "memory");
    char* buf = smem + (nt & 1) * 32768;
    f32x4 acc[4] = {{0.f,0.f,0.f,0.f},{0.f,0.f,0.f,0.f},{0.f,0.f,0.f,0.f},{0.f,0.f,0.f,0.f}};
#pragma unroll
    for (int kk = 0; kk < 8; ++kk)
#pragma unroll
      for (int t = 0; t < 4; ++t) {
        int row = t * 16 + low;
        short8 bf = *(const short8*)(buf + row * 512 + (((kk * 4 + quad) + row) & 31) * 16);
        acc[t] = __builtin_amdgcn_mfma_f32_16x16x32_bf16(af[kk], bf, acc[t], 0, 0, 0);
      }
    asm volatile("s_barrier" ::: "memory");   // all waves done reading buf
    char* Q = buf + w * 8192;                 // wave-private scratch quarter
    if (which == 2) {
      // v: 16 d-rows x 144B (n ascending bytes 0..128)
#pragma unroll
      for (int t = 0; t < 4; ++t)
#pragma unroll
        for (int rp = 0; rp < 2; ++rp) {
          uint32_t wv2;
          float f0 = acc[t][2 * rp] + bias[2 * rp];
          float f1 = acc[t][2 * rp + 1] + bias[2 * rp + 1];
          asm("v_cvt_pk_bf16_f32 %0, %1, %2" : "=v"(wv2) : "v"(f0), "v"(f1));
          *(u16*)(Q + (quad * 4 + 2 * rp) * 144 + t * 32 + low * 2) = (u16)wv2;
          *(u16*)(Q + (quad * 4 + 2 * rp + 1) * 144 + t * 32 + low * 2) = (u16)(wv2 >> 16);
        }
#pragma unroll
      for (int s = 0; s < 2; ++s) {
        int slot = s * 64 + lane;
        int row = slot >> 3, ch = slot & 7;
        short8 v8 = *(const short8*)(Q + row * 144 + ch * 16);
        *(short8*)(vv + (size_t)b * Cn * Nn + (size_t)(dl0 + w * 16 + row) * Nn +
                   n_base + nt * 64 + ch * 8) = v8;
      }
    } else {
      // q/k: 64 n-rows x 48B (16 d bf16 in bytes 0..32)
#pragma unroll
      for (int t = 0; t < 4; ++t) {
        union { uint32_t u[2]; short4v s; } pk;
        float f0 = acc[t][0] + bias[0], f1 = acc[t][1] + bias[1];
        float f2 = acc[t][2] + bias[2], f3 = acc[t][3] + bias[3];
        asm("v_cvt_pk_bf16_f32 %0, %1, %2" : "=v"(pk.u[0]) : "v"(f0), "v"(f1));
        asm("v_cvt_pk_bf16_f32 %0, %1, %2" : "=v"(pk.u[1]) : "v"(f2), "v"(f3));
        *(short4v*)(Q + (t * 16 + low) * 48 + quad * 8) = pk.s;
      }
      u16* dst = (which == 0 ? qT : kT) + (size_t)b * Nn * Cn;
#pragma unroll
      for (int s = 0; s < 2; ++s) {
        int slot = s * 64 + lane;
        int row = slot >> 1, half = slot & 1;
        short8 v8 = *(const short8*)(Q + row * 48 + half * 16);
        *(short8*)(dst + (size_t)(n_base + nt * 64 + row) * Cn + dl0 + w * 16 + half * 8) = v8;
      }
    }
  }
#undef QKV_STAGE
}

// ---------------- flash attention, pipelined double-buffered K-loop (R1) -----
// NOTE: proven local optimum. VGPR ceiling: adding live state spills (+22us,
// R2). Halving block/LDS raises L2 staging pressure faster than overlap
// (+8.5us, R5). Keep as-is.
__device__ __forceinline__ void flash_stage(char* smem, int bsel, const u16* kTb,
                                            const u16* vb, int j0, int w, int lo,
                                            int kr, int vr, int vp) {
  char* ksb = smem + bsel * 32768;
  char* vsb = ksb + 16384;
#pragma unroll
  for (int s = 0; s < 4; ++s) {   // ks: 32 rows x 512B, row-rotated chunks
    int j = kr + s * 2;
    int gc = (lo - j) & 31;
    gl_lds16(kTb + (size_t)(j0 + j) * Cn + gc * 8, ksb + (w * 8 + s * 2) * 512);
  }
#pragma unroll
  for (int s = 0; s < 4; ++s) {   // vs: 256 rows x 64B, rot(c)=c+(c>>2)
    int c = vr + s * 16;
    int gc = (vp - c - (c >> 2)) & 3;
    gl_lds16(vb + (size_t)c * Nn + j0 + gc * 8, vsb + (w * 64 + s * 16) * 64);
  }
}

__global__ __launch_bounds__(256, 2)
void k_flash(const u16* __restrict__ qT, const u16* __restrict__ kT,
             const u16* __restrict__ vv, u16* __restrict__ Op0,
             u16* __restrict__ Op1, u16* __restrict__ Op2, u16* __restrict__ Op3,
             float* __restrict__ lrow) {
  __shared__ __align__(16) char smem[65536];
  const int tid = threadIdx.x, lane = tid & 63, w = tid >> 6;
  const int lo = lane & 31, hi = lane >> 5;
  const int i0 = blockIdx.x * 128;
  const int b = blockIdx.y, jh = blockIdx.z;
  const u16* qTb = qT + (size_t)b * Nn * Cn;
  const u16* kTb = kT + (size_t)b * Nn * Cn;
  const u16* vb  = vv + (size_t)b * Cn * Nn;
  const int u7 = lo + hi;
  const int u9 = lo + hi + (lo >> 2);   // vs read rotation
  const int kr = w * 8 + hi;
  const int vr = w * 64 + (lane >> 2);
  const int vp = lane & 3;

  flash_stage(smem, 0, kTb, vb, jh * 1024, w, lo, kr, vr, vp);

  // q B-frags: lane holds q[i = i0+w*32+lo][c = ks*16 + hi*8 + e]
  short8 qf[16];
  {
    const u16* qrow = qTb + (size_t)(i0 + w * 32 + lo) * Cn + hi * 8;
#pragma unroll
    for (int ks = 0; ks < 16; ++ks) qf[ks] = *(const short8*)(qrow + ks * 16);
  }
  f32x16 Oa[8];
#pragma unroll
  for (int ct = 0; ct < 8; ++ct)
#pragma unroll
    for (int e = 0; e < 16; ++e) Oa[ct][e] = 0.f;
  float l_ = 0.f;

  for (int jt = 0; jt < 32; ++jt) {
    if (jt < 31) {
      flash_stage(smem, (jt + 1) & 1, kTb, vb, jh * 1024 + (jt + 1) * 32, w, lo, kr, vr, vp);
      asm volatile("s_waitcnt vmcnt(8)" ::: "memory");   // only the older 8 (current tile)
    } else {
      asm volatile("s_waitcnt vmcnt(0)" ::: "memory");
    }
    asm volatile("s_barrier" ::: "memory");              // raw: no vmcnt(0) drain
    const char* ksb = smem + (jt & 1) * 32768;
    const char* vsb = ksb + 16384;

    // S^T = K·q : D[m=j 32][n=i 32], A = ks (rotated), B = qf
    f32x16 S0;
#pragma unroll
    for (int e = 0; e < 16; ++e) S0[e] = 0.f;
    __builtin_amdgcn_s_setprio(1);
#pragma unroll
    for (int ks = 0; ks < 16; ++ks) {
      int ch = (ks * 2 + u7) & 31;
      short8 a0 = *(const short8*)(ksb + lo * 512 + ch * 16);
      S0 = __builtin_amdgcn_mfma_f32_32x32x16_bf16(a0, qf[ks], S0, 0, 0, 0);
    }
    __builtin_amdgcn_s_setprio(0);
    // P = exp2(S), pack bf16 pairs via v_cvt_pk_bf16_f32, per-lane l
    uint32_t Pp[8];
#pragma unroll
    for (int g = 0; g < 8; ++g) {
      float p0 = __builtin_amdgcn_exp2f(S0[2 * g]);
      float p1 = __builtin_amdgcn_exp2f(S0[2 * g + 1]);
      l_ += p0 + p1;
      asm("v_cvt_pk_bf16_f32 %0, %1, %2" : "=v"(Pp[g]) : "v"(p0), "v"(p1));
    }
    // PV: O^T[m=c][n=i] += V·P ; P B-frag via permlane32_swap half exchange
#pragma unroll
    for (int kst = 0; kst < 2; ++kst) {
      uint32_t x0 = Pp[4 * kst], x1 = Pp[4 * kst + 1];
      uint32_t y0 = Pp[4 * kst + 2], y1 = Pp[4 * kst + 3];
      asm("v_permlane32_swap_b32 %0, %1" : "+v"(x0), "+v"(y0));
      asm("v_permlane32_swap_b32 %0, %1" : "+v"(x1), "+v"(y1));
      union { uint32_t u[4]; short8 s8; } pu;
      pu.u[0] = x0;
      pu.u[1] = x1;
      pu.u[2] = y0;
      pu.u[3] = y1;
      int ch = (kst * 2 + u9) & 3;
      __builtin_amdgcn_s_setprio(1);
#pragma unroll
      for (int ct = 0; ct < 8; ++ct) {
        short8 vf = *(const short8*)(vsb + (ct * 32 + lo) * 64 + ch * 16);
        Oa[ct] = __builtin_amdgcn_mfma_f32_32x32x16_bf16(vf, pu.s8, Oa[ct], 0, 0, 0);
      }
      __builtin_amdgcn_s_setprio(0);
    }
    asm volatile("s_barrier" ::: "memory");              // readers done before restage
  }

  // l: lane pair holds complementary j halves
  l_ += __shfl_xor(l_, 32, 64);
  if (hi == 0)
    lrow[(size_t)jh * (Bn * Nn) + (size_t)b * Nn + i0 + w * 32 + lo] = l_;
  float invl = __builtin_amdgcn_rcpf(l_);
  __syncthreads();  // loop drained (vmcnt(0) at last iter); reuse all 64KB
#pragma unroll
  for (int ct = 0; ct < 8; ++ct)
#pragma unroll
    for (int g = 0; g < 4; ++g) {
      union { uint32_t u[2]; short4v s; } pk;
      float f0 = Oa[ct][g * 4 + 0] * invl, f1 = Oa[ct][g * 4 + 1] * invl;
      float f2 = Oa[ct][g * 4 + 2] * invl, f3 = Oa[ct][g * 4 + 3] * invl;
      asm("v_cvt_pk_bf16_f32 %0, %1, %2" : "=v"(pk.u[0]) : "v"(f0), "v"(f1));
      asm("v_cvt_pk_bf16_f32 %0, %1, %2" : "=v"(pk.u[1]) : "v"(f2), "v"(f3));
      int chv = (ct * 4 + g + lo) & 31;
      *(short4v*)(smem + w * 16384 + lo * 512 + chv * 16 + hi * 8) = pk.s;
    }
  __syncthreads();
  u16* Opj = (jh == 0) ? Op0 : (jh == 1) ? Op1 : (jh == 2) ? Op2 : Op3;
  u16* Ob = Opj + ((size_t)b * Nn + i0 + w * 32) * (size_t)Cn;
#pragma unroll
  for (int s = 0; s < 16; ++s) {
    int rr = s * 2 + hi;
    short8 v8 = *(const short8*)(smem + w * 16384 + rr * 512 + lo * 16);
    int gc = (lo - rr) & 31;
    *(short8*)(Ob + (size_t)rr * Cn + gc * 8) = v8;
  }
}

// ---------------- proj GEMM + bias + residual, fused 4-partial combine -------
// (R3-bench version, 191.6us total: 64x64 tile, W via gl_lds16, combine into
// swizzled B image in-block. O re-read 4x is L3-absorbed — measured neutral
// vs the read-once d-loop variant.)
__global__ __launch_bounds__(256, 2)
void k_proj(const u16* __restrict__ wpb, const float* __restrict__ bp,
            const u16* __restrict__ O0, const u16* __restrict__ O1,
            const u16* __restrict__ O2, const u16* __restrict__ O3,
            const float* __restrict__ lrow,
            const float* __restrict__ x, float* __restrict__ out) {
  __shared__ __align__(16) char smem[65536];
  int tid = threadIdx.x, lane = tid & 63, w = tid >> 6, quad = lane >> 4, low = lane & 15;
  int n0 = blockIdx.x * 64, d0 = blockIdx.y * 64, b = blockIdx.z;
  // stage W tile via gl_lds16 (swizzled source, linear dest) -> smem[0..32KB)
  {
    int r0 = w * 16;
#pragma unroll
    for (int s = 0; s < 8; ++s) {
      int rs = r0 + s * 2;
      int r = rs + (lane >> 5);
      int cb = (lane & 31) ^ (r & 7);
      gl_lds16(wpb + (size_t)(d0 + r) * Cn + cb * 8, smem + rs * 512);
    }
  }
  // combine the 4 attention partials into B tile -> smem[32KB..64KB)
#pragma unroll 4
  for (int p = 0; p < 8; ++p) {
    int slot = p * 256 + tid;          // 2048 chunk-slots
    int row = slot >> 5, pc = slot & 31;
    int gcb = pc ^ (row & 7);
    size_t gbase = ((size_t)b * Nn + n0 + row) * Cn + gcb * 8;
    short8 a0 = *(const short8*)(O0 + gbase);
    short8 a1 = *(const short8*)(O1 + gbase);
    short8 a2 = *(const short8*)(O2 + gbase);
    short8 a3 = *(const short8*)(O3 + gbase);
    int rrow = b * Nn + n0 + row;
    float L = lrow[rrow] + lrow[Bn * Nn + rrow] + lrow[2 * Bn * Nn + rrow] +
              lrow[3 * Bn * Nn + rrow];
    float inv = __builtin_amdgcn_rcpf(L);
    short8 o;
#pragma unroll
    for (int i = 0; i < 8; ++i)
      o[i] = (short)f2bf((b2f((u16)a0[i]) + b2f((u16)a1[i]) + b2f((u16)a2[i]) +
                          b2f((u16)a3[i])) * inv);
    *(short8*)(smem + 32768 + row * 512 + pc * 16) = o;
  }
  asm volatile("s_waitcnt vmcnt(0)" ::: "memory");   // W staging complete
  __syncthreads();                                   // + ds_writes visible
  f32x4 acc[4] = {{0.f,0.f,0.f,0.f},{0.f,0.f,0.f,0.f},{0.f,0.f,0.f,0.f},{0.f,0.f,0.f,0.f}};
#pragma unroll
  for (int kk = 0; kk < 8; ++kk) {
    short8 af = *(const short8*)(smem + sw512(w * 16 + low, kk * 4 + quad));
#pragma unroll
    for (int t = 0; t < 4; ++t) {
      short8 bf = *(const short8*)(smem + 32768 + sw512(t * 16 + low, kk * 4 + quad));
      acc[t] = __builtin_amdgcn_mfma_f32_16x16x32_bf16(af, bf, acc[t], 0, 0, 0);
    }
  }
  int dloc = d0 + w * 16 + quad * 4;
#pragma unroll
  for (int t = 0; t < 4; ++t)
#pragma unroll
    for (int r = 0; r < 4; ++r) {
      size_t idx = (size_t)b * Cn * Nn + (size_t)(dloc + r) * Nn + n0 + t * 16 + low;
      out[idx] = x[idx] + acc[t][r] + bp[dloc + r];
    }
}

// ---------------- launcher ----------------------------------------------------
extern "C" void kernel_launch(void* const* d_in, const int* in_sizes, int n_in,
                              void* d_out, int out_size, void* d_ws, size_t ws_size,
                              hipStream_t stream) {
  const float* x   = (const float*)d_in[0];
  const float* gsc = (const float*)d_in[1];
  const float* gbi = (const float*)d_in[2];
  const float* wq  = (const float*)d_in[3];
  const float* bq  = (const float*)d_in[4];
  const float* wk  = (const float*)d_in[5];
  const float* bk  = (const float*)d_in[6];
  const float* wv  = (const float*)d_in[7];
  const float* bv  = (const float*)d_in[8];
  const float* wp  = (const float*)d_in[9];
  const float* bp  = (const float*)d_in[10];
  float* out = (float*)d_out;

  char* ws = (char*)d_ws;
  u16*   wqkv  = (u16*)(ws + 0);          // 384 KB
  u16*   wpb   = (u16*)(ws + 393216);     // 128 KB
  float* bqkv  = (float*)(ws + 524288);   // 3 KB
  float* stats = (float*)(ws + 527360);   // 4 KB (per-part slots)
  float* lrow  = (float*)(ws + 532480);   // 256 KB
  u16*   hnT   = (u16*)(ws + 1048576);    // 8 MB; reused as Op0 after qkv
  u16*   qT    = (u16*)(ws + 9437184);    // 8 MB
  u16*   kT    = (u16*)(ws + 17825792);   // 8 MB
  u16*   vv    = (u16*)(ws + 26214400);   // 8 MB
  u16*   Op1   = (u16*)(ws + 34603008);   // 8 MB
  u16*   Op2   = (u16*)(ws + 42991616);   // 8 MB
  u16*   Op3   = (u16*)(ws + 51380224);   // 8 MB; end ~57 MB

  k_cs<<<768, 256, 0, stream>>>(wq, wk, wv, wp, bq, bk, bv, x, wqkv, wpb, bqkv, stats);
  k_apply<<<dim3(64, 4), 256, 0, stream>>>(x, stats, gsc, gbi, hnT);
  k_qkv<<<dim3(16, 12, 4), 256, 0, stream>>>(wqkv, bqkv, hnT, qT, kT, vv);
  k_flash<<<dim3(32, 4, 4), 256, 0, stream>>>(qT, kT, vv, hnT /*Op0*/, Op1, Op2, Op3, lrow);
  k_proj<<<dim3(64, 4, 4), 256, 0, stream>>>(wpb, bp, hnT /*Op0*/, Op1, Op2, Op3, lrow, x, out);
}